// Round 4
// baseline (744.649 us; speedup 1.0000x reference)
//
#include <hip/hip_runtime.h>
#include <hip/hip_bf16.h>
#include <cstdint>

typedef unsigned short u16;
typedef uint32_t u32;

constexpr int Tc = 512, Bc = 32, Vc = 4096, Sc = 128;
constexpr int BOOST = 13;    // per-step 2^13 boost folded into emissions (exactly accounted)
constexpr int BSTRIDE = 576; // blankT row stride (Tc + 64 slack)
constexpr float LOG2E = 1.4426950408889634f;
constexpr float LN2 = 0.6931471805599453f;
constexpr int NCHUNK = Tc / 64;       // 8 sync chunks (64 t-rows) per batch
constexpr int WAVES_PER_CHUNK = 16;   // 64 rows / 4 rows-per-wave

__device__ __forceinline__ float bflo(u32 p) { return __uint_as_float(p << 16); }
__device__ __forceinline__ float bfhi(u32 p) { return __uint_as_float(p & 0xffff0000u); }

__device__ __forceinline__ u32 f2bf_bits(float f) {
    __hip_bfloat16 h = __float2bfloat16(f);
    return (u32)(*reinterpret_cast<u16*>(&h));
}

// readlane -> SGPR float (index must be wave-uniform)
#define RLF(v, i) __int_as_float(__builtin_amdgcn_readlane(__float_as_int(v), (i)))

// DPP wave-max (64 lanes) -> broadcast via readlane 63.
template <int CTRL, int RMASK>
__device__ __forceinline__ float dppmax(float v) {
    int t = __builtin_amdgcn_update_dpp(__float_as_int(v), __float_as_int(v),
                                        CTRL, RMASK, 0xf, false);
    return fmaxf(v, __int_as_float(t));
}
__device__ __forceinline__ float wave_max_bcast(float v) {
    v = dppmax<0x111, 0xf>(v);   // row_shr:1
    v = dppmax<0x112, 0xf>(v);   // row_shr:2
    v = dppmax<0x114, 0xf>(v);   // row_shr:4
    v = dppmax<0x118, 0xf>(v);   // row_shr:8
    v = dppmax<0x142, 0xa>(v);   // row_bcast:15 -> rows 1,3
    v = dppmax<0x143, 0xc>(v);   // row_bcast:31 -> rows 2,3
    return __int_as_float(__builtin_amdgcn_readlane(__float_as_int(v), 63));
}

// wave-wide shift right by 1 lane; lane 0 receives 0 (bound_ctrl).
__device__ __forceinline__ float wave_shr1(float v) {
    return __int_as_float(__builtin_amdgcn_update_dpp(
        0, __float_as_int(v), 0x138, 0xf, 0xf, true));
}

// ---------------------------------------------------------------------------
// FUSED kernel (resubmission of R3 with bounded spin guard). R0/R1/R2 A/B
// established: random gather ~25us (sector-bound; dedupe/LDS/streaming all
// neutral-or-worse), ctc ~10-20us, ~320us of the timed graph is harness
// 1-GiB poison fills. Remaining lever: hide ctc under the gather wavefront.
//  - blocks 0..31: one ctc wave per b, spin-waiting on per-(b,chunk)
//    completion counters (agent-scope acquire; 2-chunk lookahead covers the
//    32-row prefetch + next-superblock blank preload). Spin is GUARDED
//    (2^26 iters ~0.1s) so any unforeseen scheduling pathology surfaces as
//    a correctness failure, never a container hang.
//  - blocks 32..1055: gather, t-major (all b progress together); each wave
//    gathers 3x4 scattered dwords for 4 t-rows, packs bf16 emit rows, then
//    release-increments its chunk counter after a device fence.
// Deadlock-free: gather never waits; ctc waits only on gather. Math is
// bit-identical to the verified kernels; only scheduling changed.
// ---------------------------------------------------------------------------
__global__ __launch_bounds__(256) void k_fused(const float* __restrict__ lp,
                                               const int* __restrict__ tgt,
                                               u32* __restrict__ emitT,
                                               float* __restrict__ blankT,
                                               u32* cnt,
                                               const int* __restrict__ in_len,
                                               const int* __restrict__ tg_len,
                                               float* __restrict__ out) {
    if (blockIdx.x >= (unsigned)Bc) {
        // ---------------- gather role ----------------
        const int g = blockIdx.x - Bc;
        const int b = g & (Bc - 1);          // b fastest: t-major block order
        const int slab = g >> 5;             // 16 t-rows per block
        const int lane = threadIdx.x & 63;
        const int wv = threadIdx.x >> 6;
        const int t0 = slab * 16 + wv * 4;   // this wave: rows t0..t0+3

        const int tg0 = tgt[b * Sc + 2 * lane];
        const int tg1 = tgt[b * Sc + 2 * lane + 1];

        const float* row0 = lp + ((size_t)t0 * Bc + b) * Vc;
        float v0[4], v1[4], vb[4];
#pragma unroll
        for (int i = 0; i < 4; ++i) {
            const float* row = row0 + (size_t)i * (Bc * Vc);
            v0[i] = row[tg0];
            v1[i] = row[tg1];
            vb[i] = row[0];                  // uniform addr -> one broadcast req
        }

        u32* orow = emitT + ((size_t)b * Tc + t0) * 64 + lane;
        float* bout = blankT + b * BSTRIDE + t0;
#pragma unroll
        for (int i = 0; i < 4; ++i) {
            const float e0 = __builtin_amdgcn_exp2f(fmaf(v0[i], LOG2E, (float)BOOST));
            const float e1 = __builtin_amdgcn_exp2f(fmaf(v1[i], LOG2E, (float)BOOST));
            orow[i * 64] = f2bf_bits(e0) | (f2bf_bits(e1) << 16);
            const float eb = __builtin_amdgcn_exp2f(fmaf(vb[i], LOG2E, (float)BOOST));
            if (lane == 0) bout[i] = eb;
        }

        __threadfence();                     // device-scope: drain + make visible
        if (lane == 0)
            __hip_atomic_fetch_add(&cnt[b * NCHUNK + (t0 >> 6)], 1u,
                                   __ATOMIC_RELEASE, __HIP_MEMORY_SCOPE_AGENT);
        return;
    }

    // ---------------- ctc role: one wave per b ----------------
    if (threadIdx.x >= 64) return;
    const int b = blockIdx.x;
    const int lane = threadIdx.x;
    const u32* p = emitT + (size_t)b * Tc * 64;
    const float* brow = blankT + b * BSTRIDE;
    const u32* cb = cnt + b * NCHUNK;
    int wlim = -1;                           // highest chunk known complete

#define WAITC(c) { int cc = (c); if (cc > NCHUNK - 1) cc = NCHUNK - 1;      \
        while (wlim < cc) { ++wlim; u32 guard = 0;                           \
            while (__hip_atomic_load(&cb[wlim], __ATOMIC_ACQUIRE,            \
                                     __HIP_MEMORY_SCOPE_AGENT) <             \
                   (u32)WAVES_PER_CHUNK) {                                   \
                if (++guard > (1u << 26)) break;   /* failsafe, never hangs */\
                __builtin_amdgcn_s_sleep(2); } } }

    // skip-transition masks (multiplicative 0/1) — from inputs, no wait
    const int tg0 = tgt[b * Sc + 2 * lane];
    const int tg1 = tgt[b * Sc + 2 * lane + 1];
    const int tgm = (lane > 0) ? tgt[b * Sc + 2 * lane - 1] : tg0;
    const float m1 = (lane > 0 && tg0 != tgm) ? 1.f : 0.f;  // j=4l+1 skip via alpha[4l-1]
    const float m3 = (tg1 != tg0) ? 1.f : 0.f;              // j=4l+3 skip via alpha[4l+1]
    const float sel = (lane == 63) ? 1.f : 0.f;             // state 256 gate

    const int steps = min(in_len[b], Tc) - 1;   // live steps: t = 1..steps

    WAITC(1)                                 // init reads rows 0..64 (chunks 0,1)

    // t = 0 init (values carry one 2^BOOST factor)
    const u32 p0 = p[lane];
    float a0 = (lane == 0) ? brow[0] : 0.f;
    float a1 = (lane == 0) ? bflo(p0) : 0.f;
    float a2 = 0.f, a3 = 0.f, a4 = 0.f;
    int e_acc = 0;

    u32 pk[32];
    const u32* pr = p + 64;                     // row t=1
#pragma unroll
    for (int d = 0; d < 32; ++d) pk[d] = pr[d * 64 + lane];
    const u32* pg = p + (size_t)33 * 64;        // refill source: row t+32 for t=1

    float blkc = brow[1 + lane];                // blanks for t = 1..64

#define RENORM() {                                                  \
        float m = fmaxf(fmaxf(fmaxf(a0, a1), fmaxf(a2, a3)), a4);   \
        m = wave_max_bcast(m);                                      \
        int e = (int)((__float_as_uint(m) >> 23) & 0xffu) - 127;    \
        float scale = __uint_as_float((u32)(127 - e) << 23);        \
        a0 *= scale; a1 *= scale; a2 *= scale;                      \
        a3 *= scale; a4 *= scale;                                   \
        e_acc += e; }

    // unmasked 16-step group; g = group index within superblock (0..3)
#define GROUP_N(g) {                                                \
        const int H = ((g) & 1) * 16;                               \
        const int BI = (g) * 16;                                    \
        _Pragma("unroll")                                           \
        for (int d = 0; d < 16; ++d) {                              \
            const u32 pv = pk[H + d];                               \
            pk[H + d] = pg[d * 64 + lane];                          \
            const float ebl = RLF(blkc, BI + d);                    \
            const float e1 = bflo(pv);                              \
            const float e3 = bfhi(pv);                              \
            const float sh = wave_shr1(a3);                         \
            const float s01 = a0 + a1;                              \
            const float s12 = a1 + a2;                              \
            const float s23 = a2 + a3;                              \
            const float n0 = ebl * (a0 + sh);                       \
            const float n1 = e1 * fmaf(m1, sh, s01);                \
            const float n3 = e3 * fmaf(m3, a1, s23);                \
            a4 = ebl * fmaf(sel, a3, a4);                           \
            a0 = n0; a1 = n1; a2 = ebl * s12; a3 = n3;              \
            if (d == 7 || d == 15) RENORM()                         \
        }                                                           \
        pg += 16 * 64; }

    // masked 16-step group (tail superblock)
#define GROUP_T(g) {                                                \
        const int H = ((g) & 1) * 16;                               \
        const int BI = (g) * 16;                                    \
        _Pragma("unroll")                                           \
        for (int d = 0; d < 16; ++d) {                              \
            const u32 pv = pk[H + d];                               \
            pk[H + d] = pg[d * 64 + lane];                          \
            const float ebl = RLF(blkc, BI + d);                    \
            const float e1 = bflo(pv);                              \
            const float e3 = bfhi(pv);                              \
            const float sh = wave_shr1(a3);                         \
            const float s01 = a0 + a1;                              \
            const float s12 = a1 + a2;                              \
            const float s23 = a2 + a3;                              \
            const float n0 = ebl * (a0 + sh);                       \
            const float n1 = e1 * fmaf(m1, sh, s01);                \
            const float n2 = ebl * s12;                             \
            const float n3 = e3 * fmaf(m3, a1, s23);                \
            const float n4 = ebl * fmaf(sel, a3, a4);               \
            const bool live = (t <= steps);                         \
            a0 = live ? n0 : a0; a1 = live ? n1 : a1;               \
            a2 = live ? n2 : a2; a3 = live ? n3 : a3;               \
            a4 = live ? n4 : a4;                                    \
            ++t;                                                    \
            if (d == 7 || d == 15) RENORM()                         \
        }                                                           \
        pg += 16 * 64; }

    const int nsb = steps >> 6;                 // full 64-step superblocks
    for (int sb = 0; sb < nsb; ++sb) {
        WAITC(sb + 2)                           // blkn lane63 touches chunk sb+2
        const float blkn = brow[(sb + 1) * 64 + 1 + lane];
        GROUP_N(0) GROUP_N(1) GROUP_N(2) GROUP_N(3)
        blkc = blkn;
    }
    // masked tail superblock (<= 64 live steps remain; renorms are
    // value-preserving on frozen alphas via e_acc accounting)
    WAITC(nsb + 2)
    int t = (nsb << 6) + 1;
    GROUP_T(0) GROUP_T(1) GROUP_T(2) GROUP_T(3)
#undef GROUP_N
#undef GROUP_T
#undef RENORM
#undef WAITC

    // terminal: ll = log(alpha[2tl] + alpha[2tl-1]) + ln2*(e_acc - BOOST*(steps+1))
    // state j -> lane j>>2, reg j&3 (j==256 -> a4 @ lane 63); tl is uniform,
    // so readlane with a uniform variable index replaces the LDS round-trip
    // (no __syncthreads -> safe with waves 1-3 exited).
    const int tl = tg_len[b];
    const int ei = 2 * tl;
    float vhi, vlo;
    if (ei >= 256) {
        vhi = RLF(a4, 63);
        vlo = RLF(a3, 63);
    } else {
        const int r = ei & 3, l = ei >> 2;
        const float x = (r == 0) ? a0 : (r == 1) ? a1 : (r == 2) ? a2 : a3;
        vhi = RLF(x, l);
        const int r2 = (ei - 1) & 3, l2 = (ei - 1) >> 2;
        const float y = (r2 == 0) ? a0 : (r2 == 1) ? a1 : (r2 == 2) ? a2 : a3;
        vlo = RLF(y, l2);
    }
    if (lane == 0) {
        const float ll = __logf(vhi + vlo) +
                         LN2 * ((float)e_acc - (float)BOOST * (float)(steps + 1));
        atomicAdd(out, ll / (float)tl / (float)Bc);
    }
}

extern "C" void kernel_launch(void* const* d_in, const int* in_sizes, int n_in,
                              void* d_out, int out_size, void* d_ws, size_t ws_size,
                              hipStream_t stream) {
    const float* lp = (const float*)d_in[0];   // (T,B,V) fp32 log-softmax
    const int* tgt = (const int*)d_in[1];      // (B,S) int32
    const int* in_len = (const int*)d_in[2];   // (B,)
    const int* tg_len = (const int*)d_in[3];   // (B,)

    char* ws = (char*)d_ws;
    float* blankT = (float*)ws;                // Bc*BSTRIDE f32 = 72 KB
    u32* cnt = (u32*)(ws + 96 * 1024);         // Bc*NCHUNK u32 = 1 KB sync counters
    u32* emitT = (u32*)(ws + 128 * 1024);      // Bc*Tc*64 u32 = 4 MB (+overread slack in ws)

    (void)hipMemsetAsync(d_out, 0, sizeof(float), stream);
    (void)hipMemsetAsync(cnt, 0, Bc * NCHUNK * sizeof(u32), stream);
    const int grid = Bc + (Tc * Bc) / 16;      // 32 ctc blocks first, 1024 gather
    k_fused<<<grid, 256, 0, stream>>>(lp, tgt, emitT, blankT, cnt,
                                      in_len, tg_len, (float*)d_out);
}

// Round 6
// 364.578 us; speedup vs baseline: 2.0425x; 2.0425x over previous
//
#include <hip/hip_runtime.h>
#include <hip/hip_bf16.h>
#include <cstdint>

typedef unsigned short u16;
typedef uint32_t u32;

constexpr int Tc = 512, Bc = 32, Vc = 4096, Sc = 128;
constexpr int BOOST = 13;    // per-step 2^13 boost folded into emissions (exactly accounted)
constexpr int BSTRIDE = 576; // blankT row stride (Tc + 64 slack)
constexpr float LOG2E = 1.4426950408889634f;
constexpr float LN2 = 0.6931471805599453f;
constexpr int NT = 4;        // t-rows gathered per wave (12 scattered loads in flight/wave)

__device__ __forceinline__ float bflo(u32 p) { return __uint_as_float(p << 16); }
__device__ __forceinline__ float bfhi(u32 p) { return __uint_as_float(p & 0xffff0000u); }

__device__ __forceinline__ u32 f2bf_bits(float f) {
    __hip_bfloat16 h = __float2bfloat16(f);
    return (u32)(*reinterpret_cast<u16*>(&h));
}

// readlane -> SGPR float (lane index is a compile-time constant after unroll)
#define RLF(v, i) __int_as_float(__builtin_amdgcn_readlane(__float_as_int(v), (i)))

// ---------------------------------------------------------------------------
// Kernel 1: direct per-lane random gather — the measured optimum (verified
// R1 configuration, 365.4us total, absmax 0.0).
// Session evidence: R0 (LDS-dedupe) == R1 (this, direct); R2 full-row
// streaming +16us; R4 fused producer/consumer +379us (agent-scope fences
// serialize at ~191 GB/s). R4's FETCH_SIZE pinned the gather traffic at
// 85.5 MB of distinct 64B sectors -> ~25us at the random-64B HBM rate.
// Caches dedupe duplicate label/line requests for free.
// ---------------------------------------------------------------------------
__global__ __launch_bounds__(256) void k_gather(const float* __restrict__ lp,
                                                const int* __restrict__ tgt,
                                                u32* __restrict__ emitT,
                                                float* __restrict__ blankT) {
    const int b = blockIdx.y;
    const int lane = threadIdx.x & 63;
    const int wv = threadIdx.x >> 6;
    const int t0 = (blockIdx.x * 4 + wv) * NT;

    const int tg0 = tgt[b * Sc + 2 * lane];
    const int tg1 = tgt[b * Sc + 2 * lane + 1];

    const float* row0 = lp + ((size_t)t0 * Bc + b) * Vc;
    float v0[NT], v1[NT], vb[NT];
#pragma unroll
    for (int i = 0; i < NT; ++i) {
        const float* row = row0 + (size_t)i * (Bc * Vc);
        v0[i] = row[tg0];
        v1[i] = row[tg1];
        vb[i] = row[0];            // same addr across lanes -> one broadcast req
    }

    u32* orow = emitT + ((size_t)b * Tc + t0) * 64 + lane;
    float* bout = blankT + b * BSTRIDE + t0;
#pragma unroll
    for (int i = 0; i < NT; ++i) {
        const float e0 = __builtin_amdgcn_exp2f(fmaf(v0[i], LOG2E, (float)BOOST));
        const float e1 = __builtin_amdgcn_exp2f(fmaf(v1[i], LOG2E, (float)BOOST));
        orow[i * 64] = f2bf_bits(e0) | (f2bf_bits(e1) << 16);
        const float eb = __builtin_amdgcn_exp2f(fmaf(vb[i], LOG2E, (float)BOOST));
        if (lane == 0) bout[i] = eb;
    }
}

// ---------------------------------------------------------------------------
// DPP wave-max (64 lanes) -> broadcast via readlane 63.
// ---------------------------------------------------------------------------
template <int CTRL, int RMASK>
__device__ __forceinline__ float dppmax(float v) {
    int t = __builtin_amdgcn_update_dpp(__float_as_int(v), __float_as_int(v),
                                        CTRL, RMASK, 0xf, false);
    return fmaxf(v, __int_as_float(t));
}
__device__ __forceinline__ float wave_max_bcast(float v) {
    v = dppmax<0x111, 0xf>(v);   // row_shr:1
    v = dppmax<0x112, 0xf>(v);   // row_shr:2
    v = dppmax<0x114, 0xf>(v);   // row_shr:4
    v = dppmax<0x118, 0xf>(v);   // row_shr:8
    v = dppmax<0x142, 0xa>(v);   // row_bcast:15 -> rows 1,3
    v = dppmax<0x143, 0xc>(v);   // row_bcast:31 -> rows 2,3
    return __int_as_float(__builtin_amdgcn_readlane(__float_as_int(v), 63));
}

// wave-wide shift right by 1 lane; lane 0 receives 0 (bound_ctrl).
__device__ __forceinline__ float wave_shr1(float v) {
    return __int_as_float(__builtin_amdgcn_update_dpp(
        0, __float_as_int(v), 0x138, 0xf, 0xf, true));
}

// ---------------------------------------------------------------------------
// Kernel 2: linear-domain CTC alpha recursion, one wave per batch element.
// Lane l owns states 4l..4l+3; state 256 rides in a4 (lane 63). Blank stream:
// ONE lane-coalesced vector load per 64 steps + per-step v_readlane (no
// wave-uniform scalar loads -> no lgkmcnt(0)-per-step drain). Emit stream:
// 32-row-deep register prefetch (slot (t-1)&31, refill row t+32).
// Renormalize by an exact power of 2 every 8 steps.
// ---------------------------------------------------------------------------
__global__ __launch_bounds__(64) void k_ctc(const u32* __restrict__ emitT,
                                            const float* __restrict__ blankT,
                                            const int* __restrict__ tgt,
                                            const int* __restrict__ in_len,
                                            const int* __restrict__ tg_len,
                                            float* __restrict__ out) {
    const int b = blockIdx.x;
    const int lane = threadIdx.x;
    const u32* p = emitT + (size_t)b * Tc * 64;
    const float* brow = blankT + b * BSTRIDE;

    // skip-transition masks (multiplicative 0/1)
    const int tg0 = tgt[b * Sc + 2 * lane];
    const int tg1 = tgt[b * Sc + 2 * lane + 1];
    const int tgm = (lane > 0) ? tgt[b * Sc + 2 * lane - 1] : tg0;
    const float m1 = (lane > 0 && tg0 != tgm) ? 1.f : 0.f;  // j=4l+1 skip via alpha[4l-1]
    const float m3 = (tg1 != tg0) ? 1.f : 0.f;              // j=4l+3 skip via alpha[4l+1]
    const float sel = (lane == 63) ? 1.f : 0.f;             // state 256 gate

    const int steps = min(in_len[b], Tc) - 1;   // live steps: t = 1..steps

    // t = 0 init (values carry one 2^BOOST factor)
    const u32 p0 = p[lane];
    float a0 = (lane == 0) ? brow[0] : 0.f;
    float a1 = (lane == 0) ? bflo(p0) : 0.f;
    float a2 = 0.f, a3 = 0.f, a4 = 0.f;
    int e_acc = 0;

    u32 pk[32];
    const u32* pr = p + 64;                     // row t=1
#pragma unroll
    for (int d = 0; d < 32; ++d) pk[d] = pr[d * 64 + lane];
    const u32* pg = p + (size_t)33 * 64;        // refill source: row t+32 for t=1

    float blkc = brow[1 + lane];                // blanks for t = 1..64

#define RENORM() {                                                  \
        float m = fmaxf(fmaxf(fmaxf(a0, a1), fmaxf(a2, a3)), a4);   \
        m = wave_max_bcast(m);                                      \
        int e = (int)((__float_as_uint(m) >> 23) & 0xffu) - 127;    \
        float scale = __uint_as_float((u32)(127 - e) << 23);        \
        a0 *= scale; a1 *= scale; a2 *= scale;                      \
        a3 *= scale; a4 *= scale;                                   \
        e_acc += e; }

    // unmasked 16-step group; g = group index within superblock (0..3)
#define GROUP_N(g) {                                                \
        const int H = ((g) & 1) * 16;                               \
        const int BI = (g) * 16;                                    \
        _Pragma("unroll")                                           \
        for (int d = 0; d < 16; ++d) {                              \
            const u32 pv = pk[H + d];                               \
            pk[H + d] = pg[d * 64 + lane];                          \
            const float ebl = RLF(blkc, BI + d);                    \
            const float e1 = bflo(pv);                              \
            const float e3 = bfhi(pv);                              \
            const float sh = wave_shr1(a3);                         \
            const float s01 = a0 + a1;                              \
            const float s12 = a1 + a2;                              \
            const float s23 = a2 + a3;                              \
            const float n0 = ebl * (a0 + sh);                       \
            const float n1 = e1 * fmaf(m1, sh, s01);                \
            const float n3 = e3 * fmaf(m3, a1, s23);                \
            a4 = ebl * fmaf(sel, a3, a4);                           \
            a0 = n0; a1 = n1; a2 = ebl * s12; a3 = n3;              \
            if (d == 7 || d == 15) RENORM()                         \
        }                                                           \
        pg += 16 * 64; }

    // masked 16-step group (tail superblock)
#define GROUP_T(g) {                                                \
        const int H = ((g) & 1) * 16;                               \
        const int BI = (g) * 16;                                    \
        _Pragma("unroll")                                           \
        for (int d = 0; d < 16; ++d) {                              \
            const u32 pv = pk[H + d];                               \
            pk[H + d] = pg[d * 64 + lane];                          \
            const float ebl = RLF(blkc, BI + d);                    \
            const float e1 = bflo(pv);                              \
            const float e3 = bfhi(pv);                              \
            const float sh = wave_shr1(a3);                         \
            const float s01 = a0 + a1;                              \
            const float s12 = a1 + a2;                              \
            const float s23 = a2 + a3;                              \
            const float n0 = ebl * (a0 + sh);                       \
            const float n1 = e1 * fmaf(m1, sh, s01);                \
            const float n2 = ebl * s12;                             \
            const float n3 = e3 * fmaf(m3, a1, s23);                \
            const float n4 = ebl * fmaf(sel, a3, a4);               \
            const bool live = (t <= steps);                         \
            a0 = live ? n0 : a0; a1 = live ? n1 : a1;               \
            a2 = live ? n2 : a2; a3 = live ? n3 : a3;               \
            a4 = live ? n4 : a4;                                    \
            ++t;                                                    \
            if (d == 7 || d == 15) RENORM()                         \
        }                                                           \
        pg += 16 * 64; }

    const int nsb = steps >> 6;                 // full 64-step superblocks
    for (int sb = 0; sb < nsb; ++sb) {
        const float blkn = brow[(sb + 1) * 64 + 1 + lane];
        GROUP_N(0) GROUP_N(1) GROUP_N(2) GROUP_N(3)
        blkc = blkn;
    }
    // masked tail superblock (<= 64 live steps remain; renorms are
    // value-preserving on frozen alphas via e_acc accounting)
    int t = (nsb << 6) + 1;
    GROUP_T(0) GROUP_T(1) GROUP_T(2) GROUP_T(3)
#undef GROUP_N
#undef GROUP_T
#undef RENORM

    // terminal: ll = log(alpha[2tl] + alpha[2tl-1]) + ln2*(e_acc - BOOST*(steps+1))
    __shared__ float sa[257];
    sa[4 * lane + 0] = a0;
    sa[4 * lane + 1] = a1;
    sa[4 * lane + 2] = a2;
    sa[4 * lane + 3] = a3;
    if (lane == 63) sa[256] = a4;
    __syncthreads();
    if (lane == 0) {
        const int tl = tg_len[b];
        const int ei = 2 * tl;
        const float ssum = sa[ei] + sa[ei - 1];
        const float ll = __logf(ssum) +
                         LN2 * ((float)e_acc - (float)BOOST * (float)(steps + 1));
        atomicAdd(out, ll / (float)tl / (float)Bc);
    }
}

extern "C" void kernel_launch(void* const* d_in, const int* in_sizes, int n_in,
                              void* d_out, int out_size, void* d_ws, size_t ws_size,
                              hipStream_t stream) {
    const float* lp = (const float*)d_in[0];   // (T,B,V) fp32 log-softmax
    const int* tgt = (const int*)d_in[1];      // (B,S) int32
    const int* in_len = (const int*)d_in[2];   // (B,)
    const int* tg_len = (const int*)d_in[3];   // (B,)

    char* ws = (char*)d_ws;
    float* blankT = (float*)ws;                // Bc*BSTRIDE f32 = 72 KB
    u32* emitT = (u32*)(ws + 128 * 1024);      // Bc*Tc*64 u32 = 4 MB (+overread slack in ws)

    (void)hipMemsetAsync(d_out, 0, sizeof(float), stream);
    k_gather<<<dim3(Tc / (4 * NT), Bc), 256, 0, stream>>>(lp, tgt, emitT, blankT);
    k_ctc<<<Bc, 64, 0, stream>>>(emitT, blankT, tgt, in_len, tg_len, (float*)d_out);
}